// Round 10
// baseline (67.770 us; speedup 1.0000x reference)
//
#include <hip/hip_runtime.h>
#include <math.h>

// Deformable conv fwd: B=4, C=CO=64, H=W=128, K=3, pad=1, stride=1.
// ws layout (float units):
//   [0, 2230272)              xh: x as bf16 NHWC with 2-px zero halo
//                                 [B][132][132][64] bf16 (8.92 MiB)
//   [2230272, 2248704)        aswz: w_def bf16 A-frags (72 KiB)
//   [2248704, 2257920)        aoff: w_off bf16 A-frags, rows padded to 32 (36 KiB)
// Panel k-order is TAP-MAJOR: ck' = tap*64 + c  (A-swizzle matches).

typedef short  v4s __attribute__((ext_vector_type(4)));
typedef short  v8s __attribute__((ext_vector_type(8)));
typedef float  v4f __attribute__((ext_vector_type(4)));
typedef float  v2f __attribute__((ext_vector_type(2)));

namespace {
constexpr int Bn = 4, Cn = 64, Hn = 128, Wn = 128, COn = 64;
constexpr int HWn = 16384;
constexpr int CKn = 576;
constexpr int TILE = 16;                // pixels per block
constexpr int RS = 580;                 // shorts per panel row = 290 dwords (≡2 mod 32)
constexpr int HW2 = 132;                // haloed width
constexpr int XPITCH = HW2 * 16;        // uint2 per halo row
constexpr size_t XH_OFF   = 0;
constexpr size_t ASWZ_OFF = 2230272;    // floats: 4*132*132*64 bf16 / 2
constexpr size_t AOFF_OFF = ASWZ_OFF + 18432;
}

__device__ __forceinline__ unsigned short f2bf(float f) {
    union { float f; unsigned int u; } v; v.f = f;
    unsigned int u = v.u;
    u += 0x7fffu + ((u >> 16) & 1u);    // RNE
    return (unsigned short)(u >> 16);
}
__device__ __forceinline__ unsigned int pack2bf(float a, float b) {
    return (unsigned int)f2bf(a) | ((unsigned int)f2bf(b) << 16);
}
__device__ __forceinline__ v2f unpk(unsigned int u) {
    v2f r;
    r.x = __uint_as_float(u << 16);
    r.y = __uint_as_float(u & 0xffff0000u);
    return r;
}

// ---- Kernel 1: NCHW fp32 -> bf16 NHWC halo buffer ----
__global__ __launch_bounds__(256) void k_halo(const float* __restrict__ x,
                                              unsigned int* __restrict__ xh) {
    __shared__ float tile[64][65];
    const int tid  = threadIdx.x;
    const int lane = tid & 63;
    const int grp  = tid >> 6;
    const int b    = blockIdx.x >> 8;
    const int hw0  = (blockIdx.x & 255) << 6;
#pragma unroll
    for (int r = 0; r < 16; ++r) {
        const int c = (r << 2) + grp;
        tile[c][lane] = x[(b * Cn + c) * HWn + hw0 + lane];
    }
    __syncthreads();
    const int h = lane >> 5;
    const int m = lane & 31;
#pragma unroll
    for (int r = 0; r < 8; ++r) {
        const int hwl = (r << 3) + (grp << 1) + h;   // 0..63
        const int hw  = hw0 + hwl;
        const int yy  = hw >> 7;
        const int xx  = hw & (Wn - 1);
        const unsigned int u = pack2bf(tile[2 * m][hwl], tile[2 * m + 1][hwl]);
        xh[((size_t)(b * HW2 + yy + 2) * HW2 + (xx + 2)) * 32 + m] = u;
    }
}

// ---- Kernel 2: weight swizzle to MFMA A-frag layout, tap-major k ----
// lane l holds A[row=16r+(l&15)][k = 32s+4(l>>4)+(j&3)+16(j>>2)], ck' = tap*64+c
__global__ __launch_bounds__(256) void k_prep(const float* __restrict__ w_def,
                                              const float* __restrict__ w_off,
                                              unsigned short* __restrict__ aswz,
                                              unsigned short* __restrict__ aoff) {
    const int idx = blockIdx.x * 256 + threadIdx.x;   // [0, 36864+18432)
    if (idx < 36864) {
        const int j = idx & 7;
        const int l = (idx >> 3) & 63;
        const int s = (idx >> 9) % 18;
        const int r = idx / 9216;
        const int co = 16 * r + (l & 15);
        const int kk = 32 * s + 4 * (l >> 4) + (j & 3) + 16 * (j >> 2);
        const int tap = kk >> 6, c = kk & 63;
        aswz[idx] = f2bf(w_def[co * CKn + c * 9 + tap]);
    } else {
        const int i2 = idx - 36864;
        const int j = i2 & 7;
        const int l = (i2 >> 3) & 63;
        const int s = (i2 >> 9) % 18;
        const int r = i2 / 9216;
        const int co = 16 * r + (l & 15);
        const int kk = 32 * s + 4 * (l >> 4) + (j & 3) + 16 * (j >> 2);
        const int tap = kk >> 6, c = kk & 63;
        aoff[i2] = (co < 18) ? f2bf(w_off[co * CKn + c * 9 + tap]) : (unsigned short)0;
    }
}

// ---- Kernel 3: fused offset MFMA + bilinear gather + output MFMA ----
__global__ __launch_bounds__(256, 6) void k_deform(const uint2* __restrict__ xh2,
                                                   const unsigned short* __restrict__ aoff,
                                                   const float* __restrict__ b_off,
                                                   const unsigned short* __restrict__ aswz,
                                                   float* __restrict__ out) {
    __shared__ unsigned short Bl[TILE * RS];   // 18560 B panel (tap-major)
    __shared__ float offl[18][16];             // 1152 B offsets  (total 19712 B < cliff)
    uint2* Bl2 = (uint2*)Bl;
    const int tid  = threadIdx.x;
    const int lane = tid & 63;
    const int wid  = tid >> 6;
    const int g    = lane >> 4;
    const int c15  = lane & 15;
    const int q    = lane & 15;     // channel-quad
    const int pq   = lane >> 4;     // pixel within wave's 4-px group
    const int b    = blockIdx.x >> 10;           // 1024 tiles per batch
    const int p0   = (blockIdx.x & 1023) * TILE; // 16 consecutive pixels (same row)
    const int pix  = (wid << 2) + pq;            // this lane's pixel (gather phases)
    const int p    = p0 + pix;
    const int oy   = p >> 7;
    const int ox   = p & (Wn - 1);
    const int xbase = b * (HW2 * HW2 * 16);      // uint2 units

    // ---- Phase 0a: regular-grid im2col panel (pure bf16 copy, in-bounds by halo) ----
#pragma unroll
    for (int k = 0; k < 9; ++k) {
        const int sy = oy + k / 3 - 1;           // in [-1,128] ⊂ halo
        const int sx = ox + k % 3 - 1;
        const uint2 t = xh2[xbase + ((sy + 2) * HW2 + (sx + 2)) * 16 + q];
        Bl2[pix * 145 + k * 16 + q] = t;
    }
    __syncthreads();

    // ---- Phase 0b: off = w_off . P via MFMA (redundant per wave; wave0 writes) ----
    {
        v4f pa00 = {0.f,0.f,0.f,0.f};
        v4f pa10 = {0.f,0.f,0.f,0.f};
#pragma unroll
        for (int s = 0; s < 18; ++s) {
            const int kb = 32 * s + 4 * g;
            const unsigned short* b0p = &Bl[c15 * RS + kb];
            const v4s lo0 = *reinterpret_cast<const v4s*>(b0p);
            const v4s hi0 = *reinterpret_cast<const v4s*>(b0p + 16);
            const v8s bb0 = {lo0[0],lo0[1],lo0[2],lo0[3],hi0[0],hi0[1],hi0[2],hi0[3]};
            const v8s a0 = *reinterpret_cast<const v8s*>(aoff + (size_t)(0 * 18 + s) * 512 + lane * 8);
            const v8s a1 = *reinterpret_cast<const v8s*>(aoff + (size_t)(1 * 18 + s) * 512 + lane * 8);
            pa00 = __builtin_amdgcn_mfma_f32_16x16x32_bf16(a0, bb0, pa00, 0, 0, 0);
            pa10 = __builtin_amdgcn_mfma_f32_16x16x32_bf16(a1, bb0, pa10, 0, 0, 0);
        }
        if (wid == 0) {
#pragma unroll
            for (int r = 0; r < 4; ++r) {
                const int co0 = (g << 2) + r;
                offl[co0][c15] = pa00[r] + b_off[co0];
                const int co1 = 16 + (g << 2) + r;
                if (co1 < 18)
                    offl[co1][c15] = pa10[r] + b_off[co1];
            }
        }
    }
    __syncthreads();

    // ---- Phase 1: bilinear gather, branch-free via halo+clamp ----
#pragma unroll
    for (int k = 0; k < 9; ++k) {
        const float py = offl[2 * k][pix]     + (float)(oy + k / 3 - 1);
        const float px = offl[2 * k + 1][pix] + (float)(ox + k % 3 - 1);
        const float fy = floorf(py);
        const float fx = floorf(px);
        const float ay = py - fy;               // in [0,1) always
        const float ax = px - fx;
        int iy0 = (int)fy;
        int ix0 = (int)fx;
        iy0 = max(-2, min(iy0, 128));           // clamped corners read halo zeros
        ix0 = max(-2, min(ix0, 128));
        const float w00 = (1.f - ay) * (1.f - ax);
        const float w01 = (1.f - ay) * ax;
        const float w10 = ay * (1.f - ax);
        const float w11 = ay * ax;
        const uint2* r0 = xh2 + xbase + ((iy0 + 2) * HW2 + (ix0 + 2)) * 16 + q;
        const uint2 u00 = r0[0];
        const uint2 u01 = r0[16];
        const uint2 u10 = r0[XPITCH];
        const uint2 u11 = r0[XPITCH + 16];
        v2f va = unpk(u00.x) * w00;
        va += unpk(u01.x) * w01;
        va += unpk(u10.x) * w10;
        va += unpk(u11.x) * w11;
        v2f vb = unpk(u00.y) * w00;
        vb += unpk(u01.y) * w01;
        vb += unpk(u10.y) * w10;
        vb += unpk(u11.y) * w11;
        Bl2[pix * 145 + k * 16 + q] = make_uint2(pack2bf(va.x, va.y), pack2bf(vb.x, vb.y));
    }
    __syncthreads();

    // ---- Phase 2: out = w_def . sampled via MFMA ----
    v4f acc0 = {0.f,0.f,0.f,0.f};
    const unsigned short* arow = aswz + (size_t)wid * 9216 + lane * 8;
#pragma unroll
    for (int s = 0; s < 18; ++s) {
        const v8s a = *reinterpret_cast<const v8s*>(arow + s * 512);
        const int kb = 32 * s + 4 * g;
        const unsigned short* b0p = &Bl[c15 * RS + kb];
        const v4s lo0 = *reinterpret_cast<const v4s*>(b0p);
        const v4s hi0 = *reinterpret_cast<const v4s*>(b0p + 16);
        const v8s bb0 = {lo0[0],lo0[1],lo0[2],lo0[3],hi0[0],hi0[1],hi0[2],hi0[3]};
        acc0 = __builtin_amdgcn_mfma_f32_16x16x32_bf16(a, bb0, acc0, 0, 0, 0);
    }
    const int co = (wid << 4) + (g << 2);
    float* op = out + ((size_t)(b * COn + co)) * HWn + p0 + c15;
#pragma unroll
    for (int r = 0; r < 4; ++r)
        op[(size_t)r * HWn] = acc0[r];
}

extern "C" void kernel_launch(void* const* d_in, const int* in_sizes, int n_in,
                              void* d_out, int out_size, void* d_ws, size_t ws_size,
                              hipStream_t stream) {
    const float* x     = (const float*)d_in[0];
    const float* w_off = (const float*)d_in[1];
    const float* b_off = (const float*)d_in[2];
    const float* w_def = (const float*)d_in[3];
    float* outp = (float*)d_out;
    float* wsf  = (float*)d_ws;
    unsigned int* xh = (unsigned int*)(wsf + XH_OFF);
    unsigned short* aswz = (unsigned short*)(wsf + ASWZ_OFF);
    unsigned short* aoff = (unsigned short*)(wsf + AOFF_OFF);

    // zero the halo buffer (borders must be 0; interior overwritten by k_halo)
    hipMemsetAsync(xh, 0, (size_t)Bn * HW2 * HW2 * Cn * 2, stream);
    k_halo<<<Bn * 256, 256, 0, stream>>>(x, xh);
    k_prep<<<216, 256, 0, stream>>>(w_def, w_off, aswz, aoff);
    k_deform<<<Bn * (HWn / TILE), 256, 0, stream>>>((const uint2*)xh, aoff, b_off, aswz, outp);
}

// Round 12
// 54.725 us; speedup vs baseline: 1.2384x; 1.2384x over previous
//
#include <hip/hip_runtime.h>
#include <math.h>

// Deformable conv fwd: B=4, C=CO=64, H=W=128, K=3, pad=1, stride=1.
// 3-kernel split: k_pre (halo+borders+weight prep) -> k_offset (offset conv
// via MFMA, off to global) -> k_main (bilinear gather + output MFMA).
// ws layout (float units):
//   [0, 2230272)              xh: x as bf16 NHWC, 2-px zero halo [B][132][132][64]
//   [2230272, 2248704)        aswz: w_def bf16 A-frags (72 KiB)
//   [2248704, 2257920)        aoff: w_off bf16 A-frags, rows padded to 32 (36 KiB)
//   [2257920, 3437568)        off_g: offsets [B][HW][18] fp32 (4.5 MiB)
// Panel k-order is TAP-MAJOR: ck' = tap*64 + c  (A-swizzle matches).

typedef short  v4s __attribute__((ext_vector_type(4)));
typedef short  v8s __attribute__((ext_vector_type(8)));
typedef float  v4f __attribute__((ext_vector_type(4)));
typedef float  v2f __attribute__((ext_vector_type(2)));

namespace {
constexpr int Bn = 4, Cn = 64, Hn = 128, Wn = 128, COn = 64;
constexpr int HWn = 16384;
constexpr int CKn = 576;
constexpr int TILE = 16;                // pixels per block
constexpr int RS = 580;                 // shorts per panel row = 290 dwords (≡2 mod 32)
constexpr int HW2 = 132;                // haloed width
constexpr int XPITCH = HW2 * 16;        // uint2 per halo row
constexpr size_t XH_OFF   = 0;
constexpr size_t ASWZ_OFF = 2230272;
constexpr size_t AOFF_OFF = ASWZ_OFF + 18432;
constexpr size_t OFFG_OFF = AOFF_OFF + 9216;
}

__device__ __forceinline__ unsigned short f2bf(float f) {
    union { float f; unsigned int u; } v; v.f = f;
    unsigned int u = v.u;
    u += 0x7fffu + ((u >> 16) & 1u);    // RNE
    return (unsigned short)(u >> 16);
}
__device__ __forceinline__ unsigned int pack2bf(float a, float b) {
    return (unsigned int)f2bf(a) | ((unsigned int)f2bf(b) << 16);
}
__device__ __forceinline__ v2f unpk(unsigned int u) {
    v2f r;
    r.x = __uint_as_float(u << 16);
    r.y = __uint_as_float(u & 0xffff0000u);
    return r;
}

// ---- Kernel 1: fused halo-transpose + weight prep + border zero ----
// blocks [0,1024): NCHW fp32 -> bf16 NHWC halo interior
// blocks [1024,1240): weight swizzle (w_def + w_off)
// blocks [1240,1500): zero halo borders
__global__ __launch_bounds__(256) void k_pre(const float* __restrict__ x,
                                             const float* __restrict__ w_def,
                                             const float* __restrict__ w_off,
                                             unsigned int* __restrict__ xh,
                                             unsigned short* __restrict__ aswz,
                                             unsigned short* __restrict__ aoff) {
    const int blk = blockIdx.x;
    const int tid = threadIdx.x;
    if (blk < 1024) {
        __shared__ float tile[64][65];
        const int lane = tid & 63;
        const int grp  = tid >> 6;
        const int b    = blk >> 8;
        const int hw0  = (blk & 255) << 6;
#pragma unroll
        for (int r = 0; r < 16; ++r) {
            const int c = (r << 2) + grp;
            tile[c][lane] = x[(b * Cn + c) * HWn + hw0 + lane];
        }
        __syncthreads();
        const int h = lane >> 5;
        const int m = lane & 31;
#pragma unroll
        for (int r = 0; r < 8; ++r) {
            const int hwl = (r << 3) + (grp << 1) + h;   // 0..63
            const int hw  = hw0 + hwl;
            const int yy  = hw >> 7;
            const int xx  = hw & (Wn - 1);
            const unsigned int u = pack2bf(tile[2 * m][hwl], tile[2 * m + 1][hwl]);
            xh[((size_t)(b * HW2 + yy + 2) * HW2 + (xx + 2)) * 32 + m] = u;
        }
    } else if (blk < 1240) {
        const int idx = (blk - 1024) * 256 + tid;   // [0, 55296)
        if (idx < 36864) {
            const int j = idx & 7;
            const int l = (idx >> 3) & 63;
            const int s = (idx >> 9) % 18;
            const int r = idx / 9216;
            const int co = 16 * r + (l & 15);
            const int kk = 32 * s + 4 * (l >> 4) + (j & 3) + 16 * (j >> 2);
            const int tap = kk >> 6, c = kk & 63;
            aswz[idx] = f2bf(w_def[co * CKn + c * 9 + tap]);
        } else {
            const int i2 = idx - 36864;
            const int j = i2 & 7;
            const int l = (i2 >> 3) & 63;
            const int s = (i2 >> 9) % 18;
            const int r = i2 / 9216;
            const int co = 16 * r + (l & 15);
            const int kk = 32 * s + 4 * (l >> 4) + (j & 3) + 16 * (j >> 2);
            const int tap = kk >> 6, c = kk & 63;
            aoff[i2] = (co < 18) ? f2bf(w_off[co * CKn + c * 9 + tap]) : (unsigned short)0;
        }
    } else {
        const int i = (blk - 1240) * 256 + tid;     // [0, 66560)
        const int b = i / 16640;
        const int r = i % 16640;
        int yy, xx, q;
        if (r < 8448) {                              // rows {0,1,130,131} full width
            const int y = r / 2112;                  // 132*16
            yy = (y < 2) ? y : 128 + y;
            const int rem = r % 2112;
            xx = rem >> 4;
            q  = rem & 15;
        } else {                                     // cols {0,1,130,131}, rows [2,130)
            const int r2 = r - 8448;
            yy = 2 + (r2 >> 6);
            const int rem = r2 & 63;
            const int xs = rem >> 4;
            xx = (xs < 2) ? xs : 128 + xs;
            q  = rem & 15;
        }
        ((uint2*)xh)[(((size_t)b * HW2 + yy) * HW2 + xx) * 16 + q] = make_uint2(0u, 0u);
    }
}

// ---- Kernel 2: offset conv via MFMA (im2col panel + k-split), off to global ----
__global__ __launch_bounds__(256, 4) void k_offset(const uint2* __restrict__ xh2,
                                                   const unsigned short* __restrict__ aoff,
                                                   const float* __restrict__ b_off,
                                                   float* __restrict__ off_g) {
    __shared__ unsigned short Bl[TILE * RS];   // 18560 B panel (tap-major)
    __shared__ float part[4][18][16];          // 4608 B partials
    uint2* Bl2 = (uint2*)Bl;
    const int tid  = threadIdx.x;
    const int lane = tid & 63;
    const int wid  = tid >> 6;
    const int g    = lane >> 4;
    const int c15  = lane & 15;
    const int q    = lane & 15;
    const int pq   = lane >> 4;
    const int b    = blockIdx.x >> 10;
    const int p0   = (blockIdx.x & 1023) * TILE;
    const int pix  = (wid << 2) + pq;
    const int p    = p0 + pix;
    const int oy   = p >> 7;
    const int ox   = p & (Wn - 1);
    const int xbase = b * (HW2 * HW2 * 16);

    // im2col panel (pure bf16 copy, in-bounds by halo)
#pragma unroll
    for (int k = 0; k < 9; ++k) {
        const int sy = oy + k / 3 - 1;
        const int sx = ox + k % 3 - 1;
        Bl2[pix * 145 + k * 16 + q] = xh2[xbase + ((sy + 2) * HW2 + (sx + 2)) * 16 + q];
    }
    __syncthreads();

    // off = w_off . P via MFMA, k-split across waves
    v4f pa0 = {0.f,0.f,0.f,0.f};
    v4f pa1 = {0.f,0.f,0.f,0.f};
    for (int s = wid; s < 18; s += 4) {
        const int kb = 32 * s + 4 * g;
        const unsigned short* b0p = &Bl[c15 * RS + kb];
        const v4s lo0 = *reinterpret_cast<const v4s*>(b0p);
        const v4s hi0 = *reinterpret_cast<const v4s*>(b0p + 16);
        const v8s bb0 = {lo0[0],lo0[1],lo0[2],lo0[3],hi0[0],hi0[1],hi0[2],hi0[3]};
        const v8s a0 = *reinterpret_cast<const v8s*>(aoff + (size_t)(0 * 18 + s) * 512 + lane * 8);
        const v8s a1 = *reinterpret_cast<const v8s*>(aoff + (size_t)(1 * 18 + s) * 512 + lane * 8);
        pa0 = __builtin_amdgcn_mfma_f32_16x16x32_bf16(a0, bb0, pa0, 0, 0, 0);
        pa1 = __builtin_amdgcn_mfma_f32_16x16x32_bf16(a1, bb0, pa1, 0, 0, 0);
    }
#pragma unroll
    for (int r = 0; r < 4; ++r) {
        const int co0 = (g << 2) + r;
        part[wid][co0][c15] = pa0[r];
        const int co1 = 16 + (g << 2) + r;
        if (co1 < 18)
            part[wid][co1][c15] = pa1[r];
    }
    __syncthreads();
    for (int idx = tid; idx < 288; idx += 256) {           // 288 = 16 px * 18 ch
        const int px = idx / 18, ch = idx % 18;
        off_g[((size_t)(b * HWn + p0)) * 18 + idx] =
            part[0][ch][px] + part[1][ch][px] + part[2][ch][px] + part[3][ch][px] + b_off[ch];
    }
}

// ---- Kernel 3: bilinear gather + output MFMA ----
__global__ __launch_bounds__(256, 4) void k_main(const uint2* __restrict__ xh2,
                                                 const float* __restrict__ off_g,
                                                 const unsigned short* __restrict__ aswz,
                                                 float* __restrict__ out) {
    __shared__ unsigned short Bl[TILE * RS];   // 18560 B panel (tap-major)
    __shared__ float offl[16][18];             // 1152 B offsets (total 19712 B)
    uint2* Bl2 = (uint2*)Bl;
    const int tid  = threadIdx.x;
    const int lane = tid & 63;
    const int wid  = tid >> 6;
    const int g    = lane >> 4;
    const int c15  = lane & 15;
    const int q    = lane & 15;
    const int pq   = lane >> 4;
    const int b    = blockIdx.x >> 10;
    const int p0   = (blockIdx.x & 1023) * TILE;
    const int pix  = (wid << 2) + pq;
    const int p    = p0 + pix;
    const int oy   = p >> 7;
    const int ox   = p & (Wn - 1);
    const int xbase = b * (HW2 * HW2 * 16);

    for (int idx = tid; idx < 288; idx += 256)             // 288 = 16 px * 18 ch
        offl[idx / 18][idx % 18] = off_g[((size_t)(b * HWn + p0)) * 18 + idx];
    __syncthreads();

    // bilinear gather, branch-free via halo+clamp
#pragma unroll
    for (int k = 0; k < 9; ++k) {
        const float py = offl[pix][2 * k]     + (float)(oy + k / 3 - 1);
        const float px = offl[pix][2 * k + 1] + (float)(ox + k % 3 - 1);
        const float fy = floorf(py);
        const float fx = floorf(px);
        const float ay = py - fy;               // in [0,1) always
        const float ax = px - fx;
        int iy0 = (int)fy;
        int ix0 = (int)fx;
        iy0 = max(-2, min(iy0, 128));           // clamped corners read halo zeros
        ix0 = max(-2, min(ix0, 128));
        const float w00 = (1.f - ay) * (1.f - ax);
        const float w01 = (1.f - ay) * ax;
        const float w10 = ay * (1.f - ax);
        const float w11 = ay * ax;
        const uint2* r0 = xh2 + xbase + ((iy0 + 2) * HW2 + (ix0 + 2)) * 16 + q;
        const uint2 u00 = r0[0];
        const uint2 u01 = r0[16];
        const uint2 u10 = r0[XPITCH];
        const uint2 u11 = r0[XPITCH + 16];
        v2f va = unpk(u00.x) * w00;
        va += unpk(u01.x) * w01;
        va += unpk(u10.x) * w10;
        va += unpk(u11.x) * w11;
        v2f vb = unpk(u00.y) * w00;
        vb += unpk(u01.y) * w01;
        vb += unpk(u10.y) * w10;
        vb += unpk(u11.y) * w11;
        Bl2[pix * 145 + k * 16 + q] = make_uint2(pack2bf(va.x, va.y), pack2bf(vb.x, vb.y));
    }
    __syncthreads();

    // out = w_def . sampled via MFMA
    v4f acc0 = {0.f,0.f,0.f,0.f};
    const unsigned short* arow = aswz + (size_t)wid * 9216 + lane * 8;
#pragma unroll
    for (int s = 0; s < 18; ++s) {
        const v8s a = *reinterpret_cast<const v8s*>(arow + s * 512);
        const int kb = 32 * s + 4 * g;
        const unsigned short* b0p = &Bl[c15 * RS + kb];
        const v4s lo0 = *reinterpret_cast<const v4s*>(b0p);
        const v4s hi0 = *reinterpret_cast<const v4s*>(b0p + 16);
        const v8s bb0 = {lo0[0],lo0[1],lo0[2],lo0[3],hi0[0],hi0[1],hi0[2],hi0[3]};
        acc0 = __builtin_amdgcn_mfma_f32_16x16x32_bf16(a, bb0, acc0, 0, 0, 0);
    }
    const int co = (wid << 4) + (g << 2);
    float* op = out + ((size_t)(b * COn + co)) * HWn + p0 + c15;
#pragma unroll
    for (int r = 0; r < 4; ++r)
        op[(size_t)r * HWn] = acc0[r];
}

extern "C" void kernel_launch(void* const* d_in, const int* in_sizes, int n_in,
                              void* d_out, int out_size, void* d_ws, size_t ws_size,
                              hipStream_t stream) {
    const float* x     = (const float*)d_in[0];
    const float* w_off = (const float*)d_in[1];
    const float* b_off = (const float*)d_in[2];
    const float* w_def = (const float*)d_in[3];
    float* outp = (float*)d_out;
    float* wsf  = (float*)d_ws;
    unsigned int* xh = (unsigned int*)(wsf + XH_OFF);
    unsigned short* aswz = (unsigned short*)(wsf + ASWZ_OFF);
    unsigned short* aoff = (unsigned short*)(wsf + AOFF_OFF);
    float* off_g = wsf + OFFG_OFF;

    k_pre<<<1500, 256, 0, stream>>>(x, w_def, w_off, xh, aswz, aoff);
    k_offset<<<Bn * (HWn / TILE), 256, 0, stream>>>((const uint2*)xh, aoff, b_off, off_g);
    k_main<<<Bn * (HWn / TILE), 256, 0, stream>>>((const uint2*)xh, off_g, aswz, outp);
}